// Round 1
// baseline (156.440 us; speedup 1.0000x reference)
//
#include <hip/hip_runtime.h>

// Length regulator: out[b, p, :] = att_out[b, idx(b,p), :] for p < total[b], else 0.
// idx(b,p) = upper_bound(csum[b], p), csum = cumsum(round(duration*alpha)).
//
// B=32, L=256, D=512, MAX_LEN=2048. Output 128 MB fp32 -> memory-bound.

constexpr int B = 32;
constexpr int L = 256;
constexpr int D = 512;
constexpr int MAX_LEN = 2048;
constexpr int POS_PER_BLOCK = 16;   // output positions per block
constexpr int THREADS = 256;        // 2 rows in flight (128 float4 lanes per row)

__global__ __launch_bounds__(THREADS) void length_regulator_kernel(
    const float* __restrict__ att_out,   // (B, L, D)
    const float* __restrict__ duration,  // (B, L)
    const int*   __restrict__ alpha_p,   // scalar
    float*       __restrict__ out)       // (B, MAX_LEN, D)
{
    __shared__ int csum[L];

    const int b        = blockIdx.y;
    const int pos_base = blockIdx.x * POS_PER_BLOCK;
    const int tid      = threadIdx.x;

    const float alpha = (float)alpha_p[0];

    // r = round-half-to-even(duration * alpha); inclusive scan in LDS.
    int v = (int)rintf(duration[b * L + tid] * alpha);
    csum[tid] = v;
    __syncthreads();
    #pragma unroll
    for (int off = 1; off < L; off <<= 1) {
        int add = (tid >= off) ? csum[tid - off] : 0;
        __syncthreads();
        csum[tid] += add;
        __syncthreads();
    }
    const int total = csum[L - 1];

    // Row copy: 128 lanes x float4 = 512 floats per row; 2 rows per pass.
    const int lane_in_row = tid & 127;
    const int row_in_pass = tid >> 7;   // 0 or 1

    const float4* __restrict__ src4 = (const float4*)(att_out + (size_t)b * L * D);
    float4*       __restrict__ dst4 = (float4*)(out + (size_t)b * MAX_LEN * D);

    #pragma unroll
    for (int i = 0; i < POS_PER_BLOCK; i += 2) {
        const int p = pos_base + i + row_in_pass;
        float4 val;
        if (p < total) {
            // upper_bound: first index with csum[idx] > p  (wave-uniform search)
            int lo = 0, hi = L;
            #pragma unroll
            while (lo < hi) {
                int mid = (lo + hi) >> 1;
                if (csum[mid] <= p) lo = mid + 1; else hi = mid;
            }
            val = src4[(size_t)lo * (D / 4) + lane_in_row];
        } else {
            val = make_float4(0.f, 0.f, 0.f, 0.f);
        }
        dst4[(size_t)p * (D / 4) + lane_in_row] = val;
    }
}

extern "C" void kernel_launch(void* const* d_in, const int* in_sizes, int n_in,
                              void* d_out, int out_size, void* d_ws, size_t ws_size,
                              hipStream_t stream) {
    const float* att_out  = (const float*)d_in[0];
    const float* duration = (const float*)d_in[1];
    const int*   alpha    = (const int*)d_in[2];
    float*       out      = (float*)d_out;

    dim3 grid(MAX_LEN / POS_PER_BLOCK, B);   // (128, 32) = 4096 blocks
    dim3 block(THREADS);
    length_regulator_kernel<<<grid, block, 0, stream>>>(att_out, duration, alpha, out);
}